// Round 12
// baseline (539.440 us; speedup 1.0000x reference)
//
#include <hip/hip_runtime.h>

#define NN 30000
#define EE 240000
#define ET 270000          // E + N self loops
#define GG 1000
#define NH 10
#define FF 78
#define HID 780
#define NEG_SLOPE 0.2f

// padded dims
#define LD_H 784           // h2 / out2 row stride (= 98*8)
#define KP_GCN 800         // A_bf row stride = 10 heads x 80 (head-padded)
#define NP_HID 896         // col-grid cover for HID-wide GEMM_B
#define KP_X 96            // FF -> mult of 32 (x_bf row stride)
#define LD_Z 960           // z row stride = 10 heads x 96
#define MP_N 30080         // NN -> mult of 128
#define MP_B 30208         // NN -> mult of 256 (gemm_b row tiles)
#define KP_P 1600          // 2*HID -> mult of 64 (GEMM_C K)
#define NP_W1 1536         // 1500 -> mult of 128
#define LD_FC 1536         // hidfc stride, mult of 64 (GEMM_D K)
#define MP_G 1024          // GG -> mult of 128

#define MT 128
#define NT 128
#define NBLK 30            // scan blocks (30000/1024)
#define EB 4               // aggregation edge batch (<64 VGPR, R10 win)

// prep_kernel segment sizes
#define C_X   (MP_N * KP_X)
#define C_WE  (NH * 128 * 96)
#define C_WC  (NP_HID * KP_GCN)
#define C_W1  (NP_W1 * KP_P)
#define C_W2  (128 * LD_FC)
#define C_PB  KP_GCN
#define C_WS  (FF * 2 * NH)
#define C_IN  NN
#define C_TOT (C_X + C_WE + C_WC + C_W1 + C_W2 + C_PB + C_WS + C_IN)

typedef __bf16 bf16_8 __attribute__((ext_vector_type(8)));
typedef float f32x4 __attribute__((ext_vector_type(4)));

__device__ __forceinline__ void async_copy16(const void* g, void* l) {
  __builtin_amdgcn_global_load_lds(
      (const __attribute__((address_space(1))) void*)g,
      (__attribute__((address_space(3))) void*)l, 16, 0, 0);
}

__device__ __forceinline__ float bf2f(unsigned int bits) {
  return __uint_as_float(bits << 16);
}

// ---------------------------------------------------------------- generic bf16 MFMA GEMM
// C[M, Nout] = A[Mpad, Kp] @ BT[Npad, Kp]^T  (+bias, relu)
// Chunk-major staging LDS [kc][r][8]; DBUF ping-pong staging; LDS-staged
// coalesced bf16 epilogue. rp > 0: XCD-partitioned 1D swizzle.
template <bool OUT_BF, int KBC, bool DBUF>
__global__ __launch_bounds__(256) void mfma_gemm(
    const __bf16* __restrict__ A, const __bf16* __restrict__ BT,
    float* __restrict__ Cf, __bf16* __restrict__ Cb,
    const float* __restrict__ bias, int M, int Kp, int Nout, int ldc,
    int relu, int rp, int nct, int mtiles) {
  constexpr int NST = KBC / 32;
  constexpr int TST = KBC / 16;
  constexpr int STAGEB = (KBC / 8) * MT * 8 * 2;
  constexpr int NEED = (DBUF ? 4 : 2) * STAGEB;
  constexpr int SMEM = NEED > 32768 ? NEED : 32768;
  __shared__ char smem[SMEM];
  int rt, ct;
  if (rp > 0) {
    int bid = blockIdx.x;
    int p = bid & 7, s = bid >> 3;
    int q = s / nct;
    rt = p * rp + q;
    ct = s - q * nct;
    if (rt >= mtiles) return;
  } else {
    rt = blockIdx.y; ct = blockIdx.x;
  }
  int row0 = rt * MT, col0 = ct * NT;
  int tid = threadIdx.x;
  int lane = tid & 63, wave = tid >> 6;
  int wm = (wave & 1) * 64, wn = (wave >> 1) * 64;
  int l15 = lane & 15, quad = lane >> 4;
  f32x4 acc[4][4] = {};

  auto stage = [&](int k0, int buf) {
    char* baseA = smem + (DBUF ? buf * 2 * STAGEB : 0);
    char* baseB = baseA + STAGEB;
    for (int t = 0; t < TST; t++) {
      int base = t * 256 + wave * 64;
      int s = base + lane;
      int kc = s >> 7, r = s & 127;
      async_copy16(A + (size_t)(row0 + r) * Kp + k0 + kc * 8,
                   baseA + (size_t)base * 16);
    }
    for (int t = 0; t < TST; t++) {
      int base = t * 256 + wave * 64;
      int s = base + lane;
      int kc = s >> 7, r = s & 127;
      async_copy16(BT + (size_t)(col0 + r) * Kp + k0 + kc * 8,
                   baseB + (size_t)base * 16);
    }
  };
  auto compute = [&](int buf) {
    char* baseA = smem + (DBUF ? buf * 2 * STAGEB : 0);
    char* baseB = baseA + STAGEB;
    for (int st = 0; st < NST; st++) {
      bf16_8 af[4], bfv[4];
      for (int mt = 0; mt < 4; mt++)
        af[mt] = *(const bf16_8*)(baseA +
            (size_t)((st * 4 + quad) * MT + wm + mt * 16 + l15) * 16);
      for (int nt = 0; nt < 4; nt++)
        bfv[nt] = *(const bf16_8*)(baseB +
            (size_t)((st * 4 + quad) * MT + wn + nt * 16 + l15) * 16);
      for (int mt = 0; mt < 4; mt++)
        for (int nt = 0; nt < 4; nt++)
          acc[mt][nt] = __builtin_amdgcn_mfma_f32_16x16x32_bf16(
              af[mt], bfv[nt], acc[mt][nt], 0, 0, 0);
    }
  };

  if (DBUF) {
    int niter = Kp / KBC;
    stage(0, 0);
    for (int k = 0; k < niter; k++) {
      __syncthreads();
      if (k + 1 < niter) stage((k + 1) * KBC, (k + 1) & 1);
      compute(k & 1);
    }
    __syncthreads();
  } else {
    for (int k0 = 0; k0 < Kp; k0 += KBC) {
      stage(k0, 0);
      __syncthreads();
      compute(0);
      __syncthreads();
    }
  }

  if (OUT_BF) {
    __bf16* Cs = (__bf16*)smem;
    for (int nt = 0; nt < 4; nt++) {
      int col_l = wn + nt * 16 + l15;
      int gcol = col0 + col_l;
      bool valid = gcol < Nout;
      float bv = (valid && bias) ? bias[gcol] : 0.f;
      int ch = col_l >> 3, wi = col_l & 7;
      for (int mt = 0; mt < 4; mt++) {
        for (int r = 0; r < 4; r++) {
          int rl = wm + mt * 16 + quad * 4 + r;
          float v = 0.f;
          if (valid) {
            v = acc[mt][nt][r] + bv;
            if (relu) v = fmaxf(v, 0.f);
          }
          Cs[rl * 128 + ((ch ^ (rl & 7)) << 3) + wi] = (__bf16)v;
        }
      }
    }
    __syncthreads();
    for (int idx = tid; idx < MT * 16; idx += 256) {
      int rl = idx >> 4, ch = idx & 15;
      int grow = row0 + rl, gcol = col0 + ch * 8;
      if (grow < M && gcol + 8 <= ldc)
        *(bf16_8*)(Cb + (size_t)grow * ldc + gcol) =
            *(const bf16_8*)&Cs[rl * 128 + ((ch ^ (rl & 7)) << 3)];
    }
  } else {
    for (int nt = 0; nt < 4; nt++) {
      int col = col0 + wn + nt * 16 + l15;
      if (col >= ldc) continue;
      bool valid = col < Nout;
      float bv = (valid && bias) ? bias[col] : 0.f;
      for (int mt = 0; mt < 4; mt++) {
        int rbase = row0 + wm + mt * 16 + quad * 4;
        for (int r = 0; r < 4; r++) {
          int row = rbase + r;
          if (row >= M) continue;
          float v = 0.f;
          if (valid) {
            v = acc[mt][nt][r] + bv;
            if (relu) v = fmaxf(v, 0.f);
          }
          Cf[(size_t)row * ldc + col] = v;
        }
      }
    }
  }
}

// ---------------------------------------------------------------- GEMM_B dedicated
// h2[NN,780] = A_bf[MP_B,800] @ WgcnT[896,800]^T.  512 threads, 256x128 tile
// (8 waves x 64x64): 2 MFLOP per 24KB staged per iter — 2.7x the generic
// kernel's intensity, attacking the barrier-drain latency plateau. DBUF 48KB
// -> 3 blocks/CU. Direct scalar epilogue (write BW not binding; R6/R8).
// h2 pad cols [780,784) left unwritten — gcn_aggr discards f>=780.
__global__ __launch_bounds__(512) void gemm_b_kernel(
    const __bf16* __restrict__ A, const __bf16* __restrict__ BT,
    __bf16* __restrict__ C) {
  __shared__ char smem[49152];           // 2 x (16KB A + 8KB B)
  int bid = blockIdx.x;
  int p = bid & 7, s = bid >> 3;
  int q = s / 7;
  int rt = p * 15 + q;
  int ct = s - q * 7;
  if (rt >= MP_B / 256) return;
  int row0 = rt * 256, col0 = ct * 128;
  int tid = threadIdx.x;
  int lane = tid & 63, wave = tid >> 6;
  int wm = (wave & 3) * 64, wn = (wave >> 2) * 64;
  int l15 = lane & 15, quad = lane >> 4;
  f32x4 acc[4][4] = {};

  auto stage = [&](int k0, int buf) {
    char* baseA = smem + buf * 24576;
    char* baseB = baseA + 16384;
    for (int t = 0; t < 2; t++) {        // A: 1024 x 16B chunks
      int base = t * 512 + wave * 64;    // wave-uniform LDS base
      int ss = base + lane;
      int kc = ss >> 8, r = ss & 255;
      async_copy16(A + (size_t)(row0 + r) * KP_GCN + k0 + kc * 8,
                   baseA + (size_t)base * 16);
    }
    {                                    // B: 512 x 16B chunks
      int base = wave * 64;
      int ss = base + lane;
      int kc = ss >> 7, r = ss & 127;
      async_copy16(BT + (size_t)(col0 + r) * KP_GCN + k0 + kc * 8,
                   baseB + (size_t)base * 16);
    }
  };
  auto compute = [&](int buf) {
    char* baseA = smem + buf * 24576;
    char* baseB = baseA + 16384;
    bf16_8 af[4], bfv[4];
    for (int mt = 0; mt < 4; mt++)
      af[mt] = *(const bf16_8*)(baseA +
          (size_t)(quad * 256 + wm + mt * 16 + l15) * 16);
    for (int nt = 0; nt < 4; nt++)
      bfv[nt] = *(const bf16_8*)(baseB +
          (size_t)(quad * 128 + wn + nt * 16 + l15) * 16);
    for (int mt = 0; mt < 4; mt++)
      for (int nt = 0; nt < 4; nt++)
        acc[mt][nt] = __builtin_amdgcn_mfma_f32_16x16x32_bf16(
            af[mt], bfv[nt], acc[mt][nt], 0, 0, 0);
  };

  constexpr int NITER = KP_GCN / 32;     // 25
  stage(0, 0);
  for (int k = 0; k < NITER; k++) {
    __syncthreads();
    if (k + 1 < NITER) stage((k + 1) * 32, (k + 1) & 1);
    compute(k & 1);
  }

  // direct epilogue: C/D layout col=lane&15, row=quad*4+reg
  for (int nt = 0; nt < 4; nt++) {
    int col = col0 + wn + nt * 16 + l15;
    if (col >= HID) continue;
    for (int mt = 0; mt < 4; mt++) {
      int rbase = row0 + wm + mt * 16 + quad * 4;
      for (int r = 0; r < 4; r++) {
        int row = rbase + r;
        if (row < NN) C[(size_t)row * LD_H + col] = (__bf16)acc[mt][nt][r];
      }
    }
  }
}

// ---------------------------------------------------------------- per-head GEMM
// A_bf[d][80h+n] = relu( z[d][96h+..] @ W_h + b_gat[78h+n] ), n<78; cols 78,79
// of each head block written 0 (pads for GEMM_B's K).
__global__ __launch_bounds__(256) void gemm_head(
    const __bf16* __restrict__ z, const __bf16* __restrict__ WE,
    const float* __restrict__ pb, __bf16* __restrict__ C) {
  __shared__ char smem[49152];
  __bf16* As = (__bf16*)smem;                     // [12][128][8]
  __bf16* Bs = (__bf16*)(smem + 24576);
  int head = blockIdx.x;
  int row0 = blockIdx.y * MT;
  int col0 = 80 * head;
  int tid = threadIdx.x;
  int lane = tid & 63, wave = tid >> 6;
  int wm = (wave & 1) * 64, wn = (wave >> 1) * 64;
  int l15 = lane & 15, quad = lane >> 4;

  for (int t = 0; t < 6; t++) {
    int base = t * 256 + wave * 64;
    int s = base + lane;
    int kc = s >> 7, r = s & 127;
    async_copy16(z + (size_t)(row0 + r) * LD_Z + 96 * head + kc * 8,
                 (char*)As + (size_t)base * 16);
  }
  for (int t = 0; t < 6; t++) {
    int base = t * 256 + wave * 64;
    int s = base + lane;
    int kc = s >> 7, r = s & 127;
    async_copy16(WE + (size_t)head * 128 * 96 + (size_t)r * 96 + kc * 8,
                 (char*)Bs + (size_t)base * 16);
  }
  __syncthreads();

  f32x4 acc[4][4] = {};
  for (int st = 0; st < 3; st++) {
    bf16_8 af[4], bfv[4];
    for (int mt = 0; mt < 4; mt++)
      af[mt] = *(const bf16_8*)&As[(size_t)((st * 4 + quad) * 128 + wm + mt * 16 + l15) * 8];
    for (int nt = 0; nt < 4; nt++)
      bfv[nt] = *(const bf16_8*)&Bs[(size_t)((st * 4 + quad) * 128 + wn + nt * 16 + l15) * 8];
    for (int mt = 0; mt < 4; mt++)
      for (int nt = 0; nt < 4; nt++)
        acc[mt][nt] = __builtin_amdgcn_mfma_f32_16x16x32_bf16(
            af[mt], bfv[nt], acc[mt][nt], 0, 0, 0);
  }
  __syncthreads();

  __bf16* Cs = (__bf16*)smem;
  for (int nt = 0; nt < 4; nt++) {
    int col_l = wn + nt * 16 + l15;
    bool valid = col_l < 78;
    float bv = valid ? pb[col0 + col_l] : 0.f;
    int ch = col_l >> 3, wi = col_l & 7;
    for (int mt = 0; mt < 4; mt++) {
      for (int r = 0; r < 4; r++) {
        int rl = wm + mt * 16 + quad * 4 + r;
        float v = valid ? fmaxf(acc[mt][nt][r] + bv, 0.f) : 0.f;
        Cs[rl * 128 + ((ch ^ (rl & 7)) << 3) + wi] = (__bf16)v;
      }
    }
  }
  __syncthreads();
  for (int idx = tid; idx < MT * 10; idx += 256) {
    int rl = idx / 10, ch = idx - rl * 10;
    int grow = row0 + rl;
    if (grow < NN)
      *(bf16_8*)(C + (size_t)grow * KP_GCN + col0 + ch * 8) =
          *(const bf16_8*)&Cs[rl * 128 + ((ch ^ (rl & 7)) << 3)];
  }
}

// ---------------------------------------------------------------- fused prep
__global__ __launch_bounds__(256) void prep_kernel(
    const float* __restrict__ x, const float* __restrict__ W_gat,
    const float* __restrict__ att_src, const float* __restrict__ att_dst,
    const float* __restrict__ W_gcn, const float* __restrict__ W1,
    const float* __restrict__ W2, const float* __restrict__ b_gat,
    __bf16* __restrict__ x_bf, __bf16* __restrict__ WE,
    __bf16* __restrict__ WgcnT, __bf16* __restrict__ W1T,
    __bf16* __restrict__ W2T, float* __restrict__ pb,
    float* __restrict__ wsd, int* __restrict__ cnt, int* __restrict__ fill,
    int* __restrict__ lo, int* __restrict__ hi) {
  int gid = blockIdx.x * 256 + threadIdx.x;
  if (gid < C_X) {
    int n = gid / KP_X, k = gid - n * KP_X;
    x_bf[gid] = (__bf16)((n < NN && k < FF) ? x[(size_t)n * FF + k] : 0.f);
    return;
  }
  gid -= C_X;
  if (gid < C_WE) {   // WE[h][n][k] = W_gat[k][78h+n], zero-padded
    int h = gid / (128 * 96);
    int rem = gid - h * 128 * 96;
    int n = rem / 96, k = rem - n * 96;
    WE[gid] = (__bf16)((n < FF && k < FF)
                           ? W_gat[(size_t)k * HID + h * FF + n] : 0.f);
    return;
  }
  gid -= C_WE;
  if (gid < C_WC) {   // WgcnT[n][k'] head-padded K: k' = 80*hh + f
    int n = gid / KP_GCN, kp = gid - n * KP_GCN;
    int hh = kp / 80, f = kp - hh * 80;
    WgcnT[gid] = (__bf16)((n < HID && f < FF)
                              ? W_gcn[(size_t)(FF * hh + f) * HID + n] : 0.f);
    return;
  }
  gid -= C_WC;
  if (gid < C_W1) {
    int n = gid / KP_P, k = gid - n * KP_P;
    W1T[gid] = (__bf16)((n < 1500 && k < 2 * HID) ? W1[(size_t)k * 1500 + n] : 0.f);
    return;
  }
  gid -= C_W1;
  if (gid < C_W2) {
    int n = gid / LD_FC, k = gid - n * LD_FC;
    W2T[gid] = (__bf16)((n < 128 && k < 1500) ? W2[(size_t)k * 128 + n] : 0.f);
    return;
  }
  gid -= C_W2;
  if (gid < C_PB) {   // head-padded bias
    int hh = gid / 80, f = gid - hh * 80;
    pb[gid] = (f < FF) ? b_gat[FF * hh + f] : 0.f;
    return;
  }
  gid -= C_PB;
  if (gid < C_WS) {
    int k = gid / (2 * NH), c = gid - k * (2 * NH);
    int h = (c < NH) ? c : c - NH;
    const float* att = (c < NH) ? att_src : att_dst;
    float s = 0.f;
    for (int f = 0; f < FF; f++)
      s += W_gat[(size_t)k * HID + h * FF + f] * att[h * FF + f];
    wsd[k * 2 * NH + c] = s;
    return;
  }
  gid -= C_WS;
  if (gid < C_IN) {
    cnt[gid] = 0; fill[gid] = 0;
    if (gid < GG) { lo[gid] = NN; hi[gid] = 0; }
  }
}

// ---------------------------------------------------------------- CSR helpers
__device__ __forceinline__ void edge_sd(const int* __restrict__ ei, int t,
                                        int& s, int& d) {
  if (t < EE) { s = ei[t]; d = ei[EE + t]; }
  else        { s = t - EE; d = t - EE; }
}

__global__ __launch_bounds__(256) void adot_count_kernel(
    const float* __restrict__ x, const float* __restrict__ wsd,
    float* __restrict__ a_src, float* __restrict__ a_dst,
    const int* __restrict__ ei, const int* __restrict__ batch,
    int* __restrict__ cnt, int* __restrict__ lo, int* __restrict__ hi) {
  __shared__ float w_s[FF * 2 * NH];
  for (int i = threadIdx.x; i < FF * 2 * NH; i += 256) w_s[i] = wsd[i];
  int gid = blockIdx.x * 256 + threadIdx.x;
  if (gid < ET) { int s, d; edge_sd(ei, gid, s, d); atomicAdd(&cnt[d], 1); }
  if (gid < NN) {
    int g = batch[gid];
    atomicMin(&lo[g], gid);
    atomicMax(&hi[g], gid + 1);
  }
  __syncthreads();
  if (gid >= NN * 2 * NH) return;
  int n = gid / (2 * NH), c = gid - n * (2 * NH);
  float s = 0.f;
  for (int k = 0; k < FF; k++) s += x[(size_t)n * FF + k] * w_s[k * 2 * NH + c];
  if (c < NH) a_src[n * NH + c] = s;
  else        a_dst[n * NH + (c - NH)] = s;
}

__global__ __launch_bounds__(1024) void scan1_kernel(
    const int* __restrict__ cnt, int* __restrict__ row_ptr,
    int* __restrict__ partial) {
  __shared__ int buf[1024];
  int i = blockIdx.x * 1024 + threadIdx.x;
  int v = (i < NN) ? cnt[i] : 0;
  buf[threadIdx.x] = v;
  __syncthreads();
  for (int off = 1; off < 1024; off <<= 1) {
    int t = (threadIdx.x >= off) ? buf[threadIdx.x - off] : 0;
    __syncthreads();
    buf[threadIdx.x] += t;
    __syncthreads();
  }
  if (i < NN) row_ptr[i] = buf[threadIdx.x] - v;
  if (threadIdx.x == 1023) partial[blockIdx.x] = buf[1023];
}

__global__ __launch_bounds__(256) void scan3_kernel(
    int* __restrict__ row_ptr, const int* __restrict__ partial,
    const int* __restrict__ cnt, float* __restrict__ dinv) {
  __shared__ int pre[NBLK];
  if (threadIdx.x == 0) {
    int run = 0;
    for (int b = 0; b < NBLK; b++) { pre[b] = run; run += partial[b]; }
  }
  __syncthreads();
  int i = blockIdx.x * 256 + threadIdx.x;
  if (i < NN) {
    row_ptr[i] += pre[i >> 10];
    dinv[i] = rsqrtf((float)max(cnt[i], 1));
  }
  if (i == 0) row_ptr[NN] = ET;
}

__global__ void scatter_kernel(const int* __restrict__ ei,
                               const int* __restrict__ row_ptr,
                               int* __restrict__ fill,
                               const float* __restrict__ a_src,
                               const float* __restrict__ a_dst,
                               int* __restrict__ col_src,
                               float* __restrict__ p_csr) {
  int t = blockIdx.x * blockDim.x + threadIdx.x;
  if (t >= ET) return;
  int s, d; edge_sd(ei, t, s, d);
  int pos = row_ptr[d] + atomicAdd(&fill[d], 1);
  col_src[pos] = s;
#pragma unroll
  for (int h = 0; h < NH; h++) {
    float v = a_src[s * NH + h] + a_dst[d * NH + h];
    v = (v > 0.f) ? v : v * NEG_SLOPE;
    p_csr[(size_t)pos * NH + h] = __expf(v);
  }
}

// ---------------------------------------------------------------- GAT x-aggregate
// z[d][96h+k] = (1/sum_h) * sum_e p[e][h] * x[src_e][k]   (k<78; pads 0)
__global__ __launch_bounds__(256) void gat_x_aggr_kernel(
    const int* __restrict__ row_ptr, const int* __restrict__ col_src,
    const float* __restrict__ p_csr, const __bf16* __restrict__ x_bf,
    __bf16* __restrict__ z) {
  int wave = threadIdx.x >> 6;
  int lane = threadIdx.x & 63;
  int d = blockIdx.x * 2 + (wave >> 1);
  int idx = (wave & 1) * 64 + lane;
  int beg = row_ptr[d], end = row_ptr[d + 1];

  if (idx < 100) {
    int h = idx / 10, j = idx - h * 10;
    int k0 = 8 * j;
    float acc[8] = {};
    float sum = 0.f;
    for (int e = beg; e < end; e += EB) {
      int sidx[EB]; float pp[EB];
#pragma unroll
      for (int q = 0; q < EB; q++) {
        bool ok = (e + q < end);
        int ee = ok ? e + q : beg;
        sidx[q] = col_src[ee];
        float p = p_csr[(size_t)ee * NH + h];
        pp[q] = ok ? p : 0.f;
      }
      uint4 rr[EB];
#pragma unroll
      for (int q = 0; q < EB; q++)
        rr[q] = *(const uint4*)(x_bf + (size_t)sidx[q] * KP_X + k0);
#pragma unroll
      for (int q = 0; q < EB; q++) {
        sum += pp[q];
        unsigned int w[4] = {rr[q].x, rr[q].y, rr[q].z, rr[q].w};
#pragma unroll
        for (int k = 0; k < 8; k++) {
          unsigned int bits = (k & 1) ? (w[k >> 1] >> 16) : (w[k >> 1] & 0xffffu);
          acc[k] += bf2f(bits) * pp[q];
        }
      }
    }
    float inv = 1.f / sum;
    bf16_8 o;
#pragma unroll
    for (int k = 0; k < 8; k++) {
      float val = (k0 + k < FF) ? acc[k] * inv : 0.f;
      o[k] = (__bf16)val;
    }
    *(bf16_8*)(z + (size_t)d * LD_Z + 96 * h + k0) = o;
  } else if (idx < 120) {   // zero-fill k in [80, 96) per head
    int t = idx - 100;
    int h = t >> 1;
    int k0 = 80 + 8 * (t & 1);
    bf16_8 zz = {};
    *(bf16_8*)(z + (size_t)d * LD_Z + 96 * h + k0) = zz;
  }
}

// ---------------------------------------------------------------- GCN aggregate
__global__ __launch_bounds__(256) void gcn_aggr_kernel(
    const int* __restrict__ row_ptr, const int* __restrict__ col_src,
    const float* __restrict__ dinv, const __bf16* __restrict__ h2,
    const float* __restrict__ b_gcn, __bf16* __restrict__ out2) {
  int wave = threadIdx.x >> 6;
  int lane = threadIdx.x & 63;
  int d = blockIdx.x * 2 + (wave >> 1);
  int half = wave & 1;
  int beg = row_ptr[d], end = row_ptr[d + 1];
  if (lane >= 49) return;
  int f0 = half * 392 + 8 * lane;
  float dv = dinv[d];
  float acc[8] = {};
  for (int e = beg; e < end; e += EB) {
    int sidx[EB]; float ww[EB];
#pragma unroll
    for (int j = 0; j < EB; j++) {
      bool ok = (e + j < end);
      int ee = ok ? e + j : beg;
      int s = col_src[ee];
      sidx[j] = s;
      ww[j] = ok ? dinv[s] * dv : 0.f;
    }
    uint4 rr[EB];
#pragma unroll
    for (int j = 0; j < EB; j++)
      rr[j] = *(const uint4*)(h2 + (size_t)sidx[j] * LD_H + f0);
#pragma unroll
    for (int j = 0; j < EB; j++) {
      unsigned int wb[4] = {rr[j].x, rr[j].y, rr[j].z, rr[j].w};
#pragma unroll
      for (int k = 0; k < 8; k++) {
        unsigned int bits = (k & 1) ? (wb[k >> 1] >> 16) : (wb[k >> 1] & 0xffffu);
        acc[k] += bf2f(bits) * ww[j];
      }
    }
  }
  bf16_8 o0;
#pragma unroll
  for (int k = 0; k < 8; k++) {
    int f = f0 + k;
    float val = (f < HID) ? fmaxf(acc[k] + b_gcn[f], 0.f) : 0.f;
    o0[k] = (__bf16)val;
  }
  *(bf16_8*)(out2 + (size_t)d * LD_H + f0) = o0;
}

// ---------------------------------------------------------------- pooling
__global__ __launch_bounds__(128) void pool_kernel(
    const __bf16* __restrict__ out2, const int* __restrict__ lo,
    const int* __restrict__ hi, __bf16* __restrict__ pooled) {
  int g = blockIdx.x;
  int l = lo[g], h = hi[g];
  int t = threadIdx.x;
  if (t >= 98) {
    if (t < 103) {   // zero pad [1560, 1600)
      int base = 1560 + (t - 98) * 8;
      for (int k = 0; k < 8; k++) pooled[(size_t)g * KP_P + base + k] = (__bf16)0.f;
    }
    return;
  }
  int f0 = 8 * t;
  float s[8] = {}, mx[8];
#pragma unroll
  for (int k = 0; k < 8; k++) mx[k] = -1e30f;
  for (int n = l; n < h; n++) {
    uint4 r = *(const uint4*)(out2 + (size_t)n * LD_H + f0);
    unsigned int w[4] = {r.x, r.y, r.z, r.w};
#pragma unroll
    for (int k = 0; k < 8; k++) {
      unsigned int bits = (k & 1) ? (w[k >> 1] >> 16) : (w[k >> 1] & 0xffffu);
      float v = bf2f(bits);
      s[k] += v;
      mx[k] = fmaxf(mx[k], v);
    }
  }
  float invc = (h > l) ? 1.f / (float)(h - l) : 0.f;
#pragma unroll
  for (int k = 0; k < 8; k++) {
    int f = f0 + k;
    if (f >= HID) continue;
    float mean = (h > l) ? s[k] * invc : 0.f;
    float mxx  = (h > l) ? mx[k] : 0.f;
    pooled[(size_t)g * KP_P + f] = (__bf16)mean;
    pooled[(size_t)g * KP_P + HID + f] = (__bf16)mxx;
  }
}

// ---------------------------------------------------------------- launch
extern "C" void kernel_launch(void* const* d_in, const int* in_sizes, int n_in,
                              void* d_out, int out_size, void* d_ws,
                              size_t ws_size, hipStream_t stream) {
  const float* x        = (const float*)d_in[0];
  const int*   edge_idx = (const int*)d_in[1];
  const int*   batch    = (const int*)d_in[2];
  const float* W_gat    = (const float*)d_in[3];
  const float* att_src  = (const float*)d_in[4];
  const float* att_dst  = (const float*)d_in[5];
  const float* b_gat    = (const float*)d_in[6];
  const float* W_gcn    = (const float*)d_in[7];
  const float* b_gcn    = (const float*)d_in[8];
  const float* W1       = (const float*)d_in[9];
  const float* b1       = (const float*)d_in[10];
  const float* W2       = (const float*)d_in[11];
  const float* b2       = (const float*)d_in[12];
  float* out = (float*)d_out;
  (void)in_sizes; (void)n_in; (void)out_size; (void)ws_size;

  char* ws = (char*)d_ws;
  size_t off = 0;
  auto alloc = [&](size_t bytes) -> void* {
    void* p = ws + off;
    off += (bytes + 255) & ~(size_t)255;
    return p;
  };
  // bufR: A_bf [MP_B][KP_GCN] (dead after GEMM_B), then out2 bf16 [NN][LD_H]
  char*  bufR     = (char*)alloc((size_t)MP_B * KP_GCN * 2);      // 48.3 MB
  __bf16* A_bf    = (__bf16*)bufR;
  __bf16* out2b   = (__bf16*)bufR;
  __bf16* z_bf    = (__bf16*)alloc((size_t)MP_B * LD_Z * 2);      // 58.0 MB
  __bf16* h2_bf   = (__bf16*)alloc((size_t)MP_N * LD_H * 2);      // 47.2 MB
  __bf16* x_bf    = (__bf16*)alloc((size_t)MP_N * KP_X * 2);      // 5.8 MB
  __bf16* WE      = (__bf16*)alloc((size_t)NH * 128 * 96 * 2);
  __bf16* WgcnT   = (__bf16*)alloc((size_t)NP_HID * KP_GCN * 2);
  __bf16* W1T     = (__bf16*)alloc((size_t)NP_W1 * KP_P * 2);
  __bf16* W2T     = (__bf16*)alloc((size_t)128 * LD_FC * 2);
  __bf16* pooled  = (__bf16*)alloc((size_t)MP_G * KP_P * 2);
  __bf16* hidfc   = (__bf16*)alloc((size_t)MP_G * LD_FC * 2);
  float* pb       = (float*)alloc((size_t)KP_GCN * 4);
  float* wsd      = (float*)alloc((size_t)FF * 2 * NH * 4);
  float* a_src_b  = (float*)alloc((size_t)NN * NH * 4);
  float* a_dst_b  = (float*)alloc((size_t)NN * NH * 4);
  float* p_csr    = (float*)alloc((size_t)ET * NH * 4);           // 10.8 MB
  int*   cnt      = (int*)alloc((size_t)NN * 4);
  int*   fill     = (int*)alloc((size_t)NN * 4);
  int*   row_ptr  = (int*)alloc((size_t)(NN + 1) * 4);
  int*   col_src  = (int*)alloc((size_t)ET * 4);
  int*   partial  = (int*)alloc((size_t)NBLK * 4);
  int*   lo       = (int*)alloc((size_t)GG * 4);
  int*   hi       = (int*)alloc((size_t)GG * 4);
  float* dinv     = (float*)alloc((size_t)NN * 4);

  prep_kernel<<<(C_TOT + 255) / 256, 256, 0, stream>>>(
      x, W_gat, att_src, att_dst, W_gcn, W1, W2, b_gat, x_bf, WE, WgcnT, W1T,
      W2T, pb, wsd, cnt, fill, lo, hi);

  adot_count_kernel<<<(NN * 2 * NH + 255) / 256, 256, 0, stream>>>(
      x, wsd, a_src_b, a_dst_b, edge_idx, batch, cnt, lo, hi);

  scan1_kernel<<<NBLK, 1024, 0, stream>>>(cnt, row_ptr, partial);
  scan3_kernel<<<(NN + 255) / 256, 256, 0, stream>>>(row_ptr, partial, cnt,
                                                     dinv);
  scatter_kernel<<<(ET + 255) / 256, 256, 0, stream>>>(
      edge_idx, row_ptr, fill, a_src_b, a_dst_b, col_src, p_csr);

  gat_x_aggr_kernel<<<NN / 2, 256, 0, stream>>>(row_ptr, col_src, p_csr, x_bf,
                                                z_bf);
  gemm_head<<<dim3(NH, MP_N / MT), 256, 0, stream>>>(z_bf, WE, pb, A_bf);
  {  // GEMM_B: 256x128 tile, DBUF, XCD swizzle — 8 x 15 x 7 = 840 blocks
    gemm_b_kernel<<<dim3(8 * 15 * 7), 512, 0, stream>>>(A_bf, WgcnT, h2_bf);
  }
  gcn_aggr_kernel<<<NN / 2, 256, 0, stream>>>(row_ptr, col_src, dinv, h2_bf,
                                              b_gcn, out2b);

  pool_kernel<<<GG, 128, 0, stream>>>(out2b, lo, hi, pooled);

  {  // GEMM_C: hidfc = relu(pooled @ W1 + b1)  (K=1600, KBC=64, DBUF)
    dim3 grid(NP_W1 / NT, MP_G / MT);
    mfma_gemm<true, 64, true><<<grid, 256, 0, stream>>>(
        pooled, W1T, nullptr, hidfc, b1, GG, KP_P, 1500, LD_FC, 1, 0, 0, 0);
  }
  {  // GEMM_D: out = hidfc @ W2 + b2  (fp32 out, K=1536, KBC=64, DBUF)
    dim3 grid(1, MP_G / MT);
    mfma_gemm<false, 64, true><<<grid, 256, 0, stream>>>(
        hidfc, W2T, out, nullptr, b2, GG, LD_FC, 128, 128, 0, 0, 0, 0);
  }
}

// Round 13
// 519.957 us; speedup vs baseline: 1.0375x; 1.0375x over previous
//
#include <hip/hip_runtime.h>

#define NN 30000
#define EE 240000
#define ET 270000          // E + N self loops
#define GG 1000
#define NH 10
#define FF 78
#define HID 780
#define NEG_SLOPE 0.2f

// padded dims
#define LD_H 784           // h2 / out2 row stride (= 98*8)
#define KP_GCN 800         // A_bf row stride = 10 heads x 80 (head-padded)
#define NP_HID 896         // col-grid cover for HID-wide GEMM_B
#define KP_X 96            // FF -> mult of 32 (x_bf row stride)
#define LD_Z 960           // z row stride = 10 heads x 96
#define MP_N 30080         // NN -> mult of 128
#define KP_P 1600          // 2*HID -> mult of 64 (GEMM_C K)
#define NP_W1 1536         // 1500 -> mult of 128
#define LD_FC 1536         // hidfc stride, mult of 64 (GEMM_D K)
#define MP_G 1024          // GG -> mult of 128

#define MT 128
#define NT 128
#define NBLK 30            // scan blocks (30000/1024)
#define EB 4               // gat_x edge batch
#define EBG 6              // gcn edge batch (est ~54 VGPR, under the 64 cliff)

// prep_kernel segment sizes
#define C_X   (MP_N * KP_X)
#define C_WE  (NH * 128 * 96)
#define C_WC  (NP_HID * KP_GCN)
#define C_W1  (NP_W1 * KP_P)
#define C_W2  (128 * LD_FC)
#define C_PB  KP_GCN
#define C_WS  (FF * 2 * NH)
#define C_IN  NN
#define C_TOT (C_X + C_WE + C_WC + C_W1 + C_W2 + C_PB + C_WS + C_IN)

typedef __bf16 bf16_8 __attribute__((ext_vector_type(8)));
typedef float f32x4 __attribute__((ext_vector_type(4)));

__device__ __forceinline__ void async_copy16(const void* g, void* l) {
  __builtin_amdgcn_global_load_lds(
      (const __attribute__((address_space(1))) void*)g,
      (__attribute__((address_space(3))) void*)l, 16, 0, 0);
}

__device__ __forceinline__ float bf2f(unsigned int bits) {
  return __uint_as_float(bits << 16);
}

// ---------------------------------------------------------------- generic bf16 MFMA GEMM
// C[M, Nout] = A[Mpad, Kp] @ BT[Npad, Kp]^T  (+bias, relu)
// Chunk-major staging LDS [kc][r][8]; DBUF ping-pong staging; LDS-staged
// coalesced bf16 epilogue. rp > 0: XCD-partitioned 1D swizzle.
// R12 lesson: per-WAVE MFMA per barrier is the latency metric — growing the
// block M-tile (R12's 256x128) doesn't change it and regressed; this 128x128
// DBUF shape is the measured best (98us on GEMM_B).
template <bool OUT_BF, int KBC, bool DBUF>
__global__ __launch_bounds__(256) void mfma_gemm(
    const __bf16* __restrict__ A, const __bf16* __restrict__ BT,
    float* __restrict__ Cf, __bf16* __restrict__ Cb,
    const float* __restrict__ bias, int M, int Kp, int Nout, int ldc,
    int relu, int rp, int nct, int mtiles) {
  constexpr int NST = KBC / 32;
  constexpr int TST = KBC / 16;
  constexpr int STAGEB = (KBC / 8) * MT * 8 * 2;
  constexpr int NEED = (DBUF ? 4 : 2) * STAGEB;
  constexpr int SMEM = NEED > 32768 ? NEED : 32768;
  __shared__ char smem[SMEM];
  int rt, ct;
  if (rp > 0) {
    int bid = blockIdx.x;
    int p = bid & 7, s = bid >> 3;
    int q = s / nct;
    rt = p * rp + q;
    ct = s - q * nct;
    if (rt >= mtiles) return;
  } else {
    rt = blockIdx.y; ct = blockIdx.x;
  }
  int row0 = rt * MT, col0 = ct * NT;
  int tid = threadIdx.x;
  int lane = tid & 63, wave = tid >> 6;
  int wm = (wave & 1) * 64, wn = (wave >> 1) * 64;
  int l15 = lane & 15, quad = lane >> 4;
  f32x4 acc[4][4] = {};

  auto stage = [&](int k0, int buf) {
    char* baseA = smem + (DBUF ? buf * 2 * STAGEB : 0);
    char* baseB = baseA + STAGEB;
    for (int t = 0; t < TST; t++) {
      int base = t * 256 + wave * 64;
      int s = base + lane;
      int kc = s >> 7, r = s & 127;
      async_copy16(A + (size_t)(row0 + r) * Kp + k0 + kc * 8,
                   baseA + (size_t)base * 16);
    }
    for (int t = 0; t < TST; t++) {
      int base = t * 256 + wave * 64;
      int s = base + lane;
      int kc = s >> 7, r = s & 127;
      async_copy16(BT + (size_t)(col0 + r) * Kp + k0 + kc * 8,
                   baseB + (size_t)base * 16);
    }
  };
  auto compute = [&](int buf) {
    char* baseA = smem + (DBUF ? buf * 2 * STAGEB : 0);
    char* baseB = baseA + STAGEB;
    for (int st = 0; st < NST; st++) {
      bf16_8 af[4], bfv[4];
      for (int mt = 0; mt < 4; mt++)
        af[mt] = *(const bf16_8*)(baseA +
            (size_t)((st * 4 + quad) * MT + wm + mt * 16 + l15) * 16);
      for (int nt = 0; nt < 4; nt++)
        bfv[nt] = *(const bf16_8*)(baseB +
            (size_t)((st * 4 + quad) * MT + wn + nt * 16 + l15) * 16);
      for (int mt = 0; mt < 4; mt++)
        for (int nt = 0; nt < 4; nt++)
          acc[mt][nt] = __builtin_amdgcn_mfma_f32_16x16x32_bf16(
              af[mt], bfv[nt], acc[mt][nt], 0, 0, 0);
    }
  };

  if (DBUF) {
    int niter = Kp / KBC;
    stage(0, 0);
    for (int k = 0; k < niter; k++) {
      __syncthreads();
      if (k + 1 < niter) stage((k + 1) * KBC, (k + 1) & 1);
      compute(k & 1);
    }
    __syncthreads();
  } else {
    for (int k0 = 0; k0 < Kp; k0 += KBC) {
      stage(k0, 0);
      __syncthreads();
      compute(0);
      __syncthreads();
    }
  }

  if (OUT_BF) {
    __bf16* Cs = (__bf16*)smem;
    for (int nt = 0; nt < 4; nt++) {
      int col_l = wn + nt * 16 + l15;
      int gcol = col0 + col_l;
      bool valid = gcol < Nout;
      float bv = (valid && bias) ? bias[gcol] : 0.f;
      int ch = col_l >> 3, wi = col_l & 7;
      for (int mt = 0; mt < 4; mt++) {
        for (int r = 0; r < 4; r++) {
          int rl = wm + mt * 16 + quad * 4 + r;
          float v = 0.f;
          if (valid) {
            v = acc[mt][nt][r] + bv;
            if (relu) v = fmaxf(v, 0.f);
          }
          Cs[rl * 128 + ((ch ^ (rl & 7)) << 3) + wi] = (__bf16)v;
        }
      }
    }
    __syncthreads();
    for (int idx = tid; idx < MT * 16; idx += 256) {
      int rl = idx >> 4, ch = idx & 15;
      int grow = row0 + rl, gcol = col0 + ch * 8;
      if (grow < M && gcol + 8 <= ldc)
        *(bf16_8*)(Cb + (size_t)grow * ldc + gcol) =
            *(const bf16_8*)&Cs[rl * 128 + ((ch ^ (rl & 7)) << 3)];
    }
  } else {
    for (int nt = 0; nt < 4; nt++) {
      int col = col0 + wn + nt * 16 + l15;
      if (col >= ldc) continue;
      bool valid = col < Nout;
      float bv = (valid && bias) ? bias[col] : 0.f;
      for (int mt = 0; mt < 4; mt++) {
        int rbase = row0 + wm + mt * 16 + quad * 4;
        for (int r = 0; r < 4; r++) {
          int row = rbase + r;
          if (row >= M) continue;
          float v = 0.f;
          if (valid) {
            v = acc[mt][nt][r] + bv;
            if (relu) v = fmaxf(v, 0.f);
          }
          Cf[(size_t)row * ldc + col] = v;
        }
      }
    }
  }
}

// ---------------------------------------------------------------- per-head GEMM
// A_bf[d][80h+n] = relu( z[d][96h+..] @ W_h + b_gat[78h+n] ), n<78; cols 78,79
// of each head block written 0 (pads for GEMM_B's K).
__global__ __launch_bounds__(256) void gemm_head(
    const __bf16* __restrict__ z, const __bf16* __restrict__ WE,
    const float* __restrict__ pb, __bf16* __restrict__ C) {
  __shared__ char smem[49152];
  __bf16* As = (__bf16*)smem;                     // [12][128][8]
  __bf16* Bs = (__bf16*)(smem + 24576);
  int head = blockIdx.x;
  int row0 = blockIdx.y * MT;
  int col0 = 80 * head;
  int tid = threadIdx.x;
  int lane = tid & 63, wave = tid >> 6;
  int wm = (wave & 1) * 64, wn = (wave >> 1) * 64;
  int l15 = lane & 15, quad = lane >> 4;

  for (int t = 0; t < 6; t++) {
    int base = t * 256 + wave * 64;
    int s = base + lane;
    int kc = s >> 7, r = s & 127;
    async_copy16(z + (size_t)(row0 + r) * LD_Z + 96 * head + kc * 8,
                 (char*)As + (size_t)base * 16);
  }
  for (int t = 0; t < 6; t++) {
    int base = t * 256 + wave * 64;
    int s = base + lane;
    int kc = s >> 7, r = s & 127;
    async_copy16(WE + (size_t)head * 128 * 96 + (size_t)r * 96 + kc * 8,
                 (char*)Bs + (size_t)base * 16);
  }
  __syncthreads();

  f32x4 acc[4][4] = {};
  for (int st = 0; st < 3; st++) {
    bf16_8 af[4], bfv[4];
    for (int mt = 0; mt < 4; mt++)
      af[mt] = *(const bf16_8*)&As[(size_t)((st * 4 + quad) * 128 + wm + mt * 16 + l15) * 8];
    for (int nt = 0; nt < 4; nt++)
      bfv[nt] = *(const bf16_8*)&Bs[(size_t)((st * 4 + quad) * 128 + wn + nt * 16 + l15) * 8];
    for (int mt = 0; mt < 4; mt++)
      for (int nt = 0; nt < 4; nt++)
        acc[mt][nt] = __builtin_amdgcn_mfma_f32_16x16x32_bf16(
            af[mt], bfv[nt], acc[mt][nt], 0, 0, 0);
  }
  __syncthreads();

  __bf16* Cs = (__bf16*)smem;
  for (int nt = 0; nt < 4; nt++) {
    int col_l = wn + nt * 16 + l15;
    bool valid = col_l < 78;
    float bv = valid ? pb[col0 + col_l] : 0.f;
    int ch = col_l >> 3, wi = col_l & 7;
    for (int mt = 0; mt < 4; mt++) {
      for (int r = 0; r < 4; r++) {
        int rl = wm + mt * 16 + quad * 4 + r;
        float v = valid ? fmaxf(acc[mt][nt][r] + bv, 0.f) : 0.f;
        Cs[rl * 128 + ((ch ^ (rl & 7)) << 3) + wi] = (__bf16)v;
      }
    }
  }
  __syncthreads();
  for (int idx = tid; idx < MT * 10; idx += 256) {
    int rl = idx / 10, ch = idx - rl * 10;
    int grow = row0 + rl;
    if (grow < NN)
      *(bf16_8*)(C + (size_t)grow * KP_GCN + col0 + ch * 8) =
          *(const bf16_8*)&Cs[rl * 128 + ((ch ^ (rl & 7)) << 3)];
  }
}

// ---------------------------------------------------------------- fused prep
__global__ __launch_bounds__(256) void prep_kernel(
    const float* __restrict__ x, const float* __restrict__ W_gat,
    const float* __restrict__ att_src, const float* __restrict__ att_dst,
    const float* __restrict__ W_gcn, const float* __restrict__ W1,
    const float* __restrict__ W2, const float* __restrict__ b_gat,
    __bf16* __restrict__ x_bf, __bf16* __restrict__ WE,
    __bf16* __restrict__ WgcnT, __bf16* __restrict__ W1T,
    __bf16* __restrict__ W2T, float* __restrict__ pb,
    float* __restrict__ wsd, int* __restrict__ cnt, int* __restrict__ fill,
    int* __restrict__ lo, int* __restrict__ hi) {
  int gid = blockIdx.x * 256 + threadIdx.x;
  if (gid < C_X) {
    int n = gid / KP_X, k = gid - n * KP_X;
    x_bf[gid] = (__bf16)((n < NN && k < FF) ? x[(size_t)n * FF + k] : 0.f);
    return;
  }
  gid -= C_X;
  if (gid < C_WE) {   // WE[h][n][k] = W_gat[k][78h+n], zero-padded
    int h = gid / (128 * 96);
    int rem = gid - h * 128 * 96;
    int n = rem / 96, k = rem - n * 96;
    WE[gid] = (__bf16)((n < FF && k < FF)
                           ? W_gat[(size_t)k * HID + h * FF + n] : 0.f);
    return;
  }
  gid -= C_WE;
  if (gid < C_WC) {   // WgcnT[n][k'] head-padded K: k' = 80*hh + f
    int n = gid / KP_GCN, kp = gid - n * KP_GCN;
    int hh = kp / 80, f = kp - hh * 80;
    WgcnT[gid] = (__bf16)((n < HID && f < FF)
                              ? W_gcn[(size_t)(FF * hh + f) * HID + n] : 0.f);
    return;
  }
  gid -= C_WC;
  if (gid < C_W1) {
    int n = gid / KP_P, k = gid - n * KP_P;
    W1T[gid] = (__bf16)((n < 1500 && k < 2 * HID) ? W1[(size_t)k * 1500 + n] : 0.f);
    return;
  }
  gid -= C_W1;
  if (gid < C_W2) {
    int n = gid / LD_FC, k = gid - n * LD_FC;
    W2T[gid] = (__bf16)((n < 128 && k < 1500) ? W2[(size_t)k * 128 + n] : 0.f);
    return;
  }
  gid -= C_W2;
  if (gid < C_PB) {   // head-padded bias
    int hh = gid / 80, f = gid - hh * 80;
    pb[gid] = (f < FF) ? b_gat[FF * hh + f] : 0.f;
    return;
  }
  gid -= C_PB;
  if (gid < C_WS) {
    int k = gid / (2 * NH), c = gid - k * (2 * NH);
    int h = (c < NH) ? c : c - NH;
    const float* att = (c < NH) ? att_src : att_dst;
    float s = 0.f;
    for (int f = 0; f < FF; f++)
      s += W_gat[(size_t)k * HID + h * FF + f] * att[h * FF + f];
    wsd[k * 2 * NH + c] = s;
    return;
  }
  gid -= C_WS;
  if (gid < C_IN) {
    cnt[gid] = 0; fill[gid] = 0;
    if (gid < GG) { lo[gid] = NN; hi[gid] = 0; }
  }
}

// ---------------------------------------------------------------- CSR helpers
__device__ __forceinline__ void edge_sd(const int* __restrict__ ei, int t,
                                        int& s, int& d) {
  if (t < EE) { s = ei[t]; d = ei[EE + t]; }
  else        { s = t - EE; d = t - EE; }
}

__global__ __launch_bounds__(256) void adot_count_kernel(
    const float* __restrict__ x, const float* __restrict__ wsd,
    float* __restrict__ a_src, float* __restrict__ a_dst,
    const int* __restrict__ ei, const int* __restrict__ batch,
    int* __restrict__ cnt, int* __restrict__ lo, int* __restrict__ hi) {
  __shared__ float w_s[FF * 2 * NH];
  for (int i = threadIdx.x; i < FF * 2 * NH; i += 256) w_s[i] = wsd[i];
  int gid = blockIdx.x * 256 + threadIdx.x;
  if (gid < ET) { int s, d; edge_sd(ei, gid, s, d); atomicAdd(&cnt[d], 1); }
  if (gid < NN) {
    int g = batch[gid];
    atomicMin(&lo[g], gid);
    atomicMax(&hi[g], gid + 1);
  }
  __syncthreads();
  if (gid >= NN * 2 * NH) return;
  int n = gid / (2 * NH), c = gid - n * (2 * NH);
  float s = 0.f;
  for (int k = 0; k < FF; k++) s += x[(size_t)n * FF + k] * w_s[k * 2 * NH + c];
  if (c < NH) a_src[n * NH + c] = s;
  else        a_dst[n * NH + (c - NH)] = s;
}

__global__ __launch_bounds__(1024) void scan1_kernel(
    const int* __restrict__ cnt, int* __restrict__ row_ptr,
    int* __restrict__ partial) {
  __shared__ int buf[1024];
  int i = blockIdx.x * 1024 + threadIdx.x;
  int v = (i < NN) ? cnt[i] : 0;
  buf[threadIdx.x] = v;
  __syncthreads();
  for (int off = 1; off < 1024; off <<= 1) {
    int t = (threadIdx.x >= off) ? buf[threadIdx.x - off] : 0;
    __syncthreads();
    buf[threadIdx.x] += t;
    __syncthreads();
  }
  if (i < NN) row_ptr[i] = buf[threadIdx.x] - v;
  if (threadIdx.x == 1023) partial[blockIdx.x] = buf[1023];
}

__global__ __launch_bounds__(256) void scan3_kernel(
    int* __restrict__ row_ptr, const int* __restrict__ partial,
    const int* __restrict__ cnt, float* __restrict__ dinv) {
  __shared__ int pre[NBLK];
  if (threadIdx.x == 0) {
    int run = 0;
    for (int b = 0; b < NBLK; b++) { pre[b] = run; run += partial[b]; }
  }
  __syncthreads();
  int i = blockIdx.x * 256 + threadIdx.x;
  if (i < NN) {
    row_ptr[i] += pre[i >> 10];
    dinv[i] = rsqrtf((float)max(cnt[i], 1));
  }
  if (i == 0) row_ptr[NN] = ET;
}

// scatter: only 8B random writes per edge (col_src + dst_csr);
// p computed CSR-ordered in pexp_kernel (coalesced 40B writes).
__global__ void scatter_kernel(const int* __restrict__ ei,
                               const int* __restrict__ row_ptr,
                               int* __restrict__ fill,
                               int* __restrict__ col_src,
                               int* __restrict__ dst_csr) {
  int t = blockIdx.x * blockDim.x + threadIdx.x;
  if (t >= ET) return;
  int s, d; edge_sd(ei, t, s, d);
  int pos = row_ptr[d] + atomicAdd(&fill[d], 1);
  col_src[pos] = s;
  dst_csr[pos] = d;
}

__global__ void pexp_kernel(const int* __restrict__ col_src,
                            const int* __restrict__ dst_csr,
                            const float* __restrict__ a_src,
                            const float* __restrict__ a_dst,
                            float* __restrict__ p_csr) {
  int t = blockIdx.x * blockDim.x + threadIdx.x;
  if (t >= ET) return;
  int s = col_src[t], d = dst_csr[t];
#pragma unroll
  for (int h = 0; h < NH; h++) {
    float v = a_src[s * NH + h] + a_dst[d * NH + h];
    v = (v > 0.f) ? v : v * NEG_SLOPE;
    p_csr[(size_t)t * NH + h] = __expf(v);
  }
}

// ---------------------------------------------------------------- GAT x-aggregate
// z[d][96h+k] = (1/sum_h) * sum_e p[e][h] * x[src_e][k]   (k<78; pads 0)
__global__ __launch_bounds__(256) void gat_x_aggr_kernel(
    const int* __restrict__ row_ptr, const int* __restrict__ col_src,
    const float* __restrict__ p_csr, const __bf16* __restrict__ x_bf,
    __bf16* __restrict__ z) {
  int wave = threadIdx.x >> 6;
  int lane = threadIdx.x & 63;
  int d = blockIdx.x * 2 + (wave >> 1);
  int idx = (wave & 1) * 64 + lane;
  int beg = row_ptr[d], end = row_ptr[d + 1];

  if (idx < 100) {
    int h = idx / 10, j = idx - h * 10;
    int k0 = 8 * j;
    float acc[8] = {};
    float sum = 0.f;
    for (int e = beg; e < end; e += EB) {
      int sidx[EB]; float pp[EB];
#pragma unroll
      for (int q = 0; q < EB; q++) {
        bool ok = (e + q < end);
        int ee = ok ? e + q : beg;
        sidx[q] = col_src[ee];
        float p = p_csr[(size_t)ee * NH + h];
        pp[q] = ok ? p : 0.f;
      }
      uint4 rr[EB];
#pragma unroll
      for (int q = 0; q < EB; q++)
        rr[q] = *(const uint4*)(x_bf + (size_t)sidx[q] * KP_X + k0);
#pragma unroll
      for (int q = 0; q < EB; q++) {
        sum += pp[q];
        unsigned int w[4] = {rr[q].x, rr[q].y, rr[q].z, rr[q].w};
#pragma unroll
        for (int k = 0; k < 8; k++) {
          unsigned int bits = (k & 1) ? (w[k >> 1] >> 16) : (w[k >> 1] & 0xffffu);
          acc[k] += bf2f(bits) * pp[q];
        }
      }
    }
    float inv = 1.f / sum;
    bf16_8 o;
#pragma unroll
    for (int k = 0; k < 8; k++) {
      float val = (k0 + k < FF) ? acc[k] * inv : 0.f;
      o[k] = (__bf16)val;
    }
    *(bf16_8*)(z + (size_t)d * LD_Z + 96 * h + k0) = o;
  } else if (idx < 120) {   // zero-fill k in [80, 96) per head
    int t = idx - 100;
    int h = t >> 1;
    int k0 = 80 + 8 * (t & 1);
    bf16_8 zz = {};
    *(bf16_8*)(z + (size_t)d * LD_Z + 96 * h + k0) = zz;
  }
}

// ---------------------------------------------------------------- GCN aggregate
__global__ __launch_bounds__(256) void gcn_aggr_kernel(
    const int* __restrict__ row_ptr, const int* __restrict__ col_src,
    const float* __restrict__ dinv, const __bf16* __restrict__ h2,
    const float* __restrict__ b_gcn, __bf16* __restrict__ out2) {
  int wave = threadIdx.x >> 6;
  int lane = threadIdx.x & 63;
  int d = blockIdx.x * 2 + (wave >> 1);
  int half = wave & 1;
  int beg = row_ptr[d], end = row_ptr[d + 1];
  if (lane >= 49) return;
  int f0 = half * 392 + 8 * lane;
  float dv = dinv[d];
  float acc[8] = {};
  for (int e = beg; e < end; e += EBG) {
    int sidx[EBG]; float ww[EBG];
#pragma unroll
    for (int j = 0; j < EBG; j++) {
      bool ok = (e + j < end);
      int ee = ok ? e + j : beg;
      int s = col_src[ee];
      sidx[j] = s;
      ww[j] = ok ? dinv[s] * dv : 0.f;
    }
    uint4 rr[EBG];
#pragma unroll
    for (int j = 0; j < EBG; j++)
      rr[j] = *(const uint4*)(h2 + (size_t)sidx[j] * LD_H + f0);
#pragma unroll
    for (int j = 0; j < EBG; j++) {
      unsigned int wb[4] = {rr[j].x, rr[j].y, rr[j].z, rr[j].w};
#pragma unroll
      for (int k = 0; k < 8; k++) {
        unsigned int bits = (k & 1) ? (wb[k >> 1] >> 16) : (wb[k >> 1] & 0xffffu);
        acc[k] += bf2f(bits) * ww[j];
      }
    }
  }
  bf16_8 o0;
#pragma unroll
  for (int k = 0; k < 8; k++) {
    int f = f0 + k;
    float val = (f < HID) ? fmaxf(acc[k] + b_gcn[f], 0.f) : 0.f;
    o0[k] = (__bf16)val;
  }
  *(bf16_8*)(out2 + (size_t)d * LD_H + f0) = o0;
}

// ---------------------------------------------------------------- pooling
__global__ __launch_bounds__(128) void pool_kernel(
    const __bf16* __restrict__ out2, const int* __restrict__ lo,
    const int* __restrict__ hi, __bf16* __restrict__ pooled) {
  int g = blockIdx.x;
  int l = lo[g], h = hi[g];
  int t = threadIdx.x;
  if (t >= 98) {
    if (t < 103) {   // zero pad [1560, 1600)
      int base = 1560 + (t - 98) * 8;
      for (int k = 0; k < 8; k++) pooled[(size_t)g * KP_P + base + k] = (__bf16)0.f;
    }
    return;
  }
  int f0 = 8 * t;
  float s[8] = {}, mx[8];
#pragma unroll
  for (int k = 0; k < 8; k++) mx[k] = -1e30f;
  for (int n = l; n < h; n++) {
    uint4 r = *(const uint4*)(out2 + (size_t)n * LD_H + f0);
    unsigned int w[4] = {r.x, r.y, r.z, r.w};
#pragma unroll
    for (int k = 0; k < 8; k++) {
      unsigned int bits = (k & 1) ? (w[k >> 1] >> 16) : (w[k >> 1] & 0xffffu);
      float v = bf2f(bits);
      s[k] += v;
      mx[k] = fmaxf(mx[k], v);
    }
  }
  float invc = (h > l) ? 1.f / (float)(h - l) : 0.f;
#pragma unroll
  for (int k = 0; k < 8; k++) {
    int f = f0 + k;
    if (f >= HID) continue;
    float mean = (h > l) ? s[k] * invc : 0.f;
    float mxx  = (h > l) ? mx[k] : 0.f;
    pooled[(size_t)g * KP_P + f] = (__bf16)mean;
    pooled[(size_t)g * KP_P + HID + f] = (__bf16)mxx;
  }
}

// ---------------------------------------------------------------- launch
extern "C" void kernel_launch(void* const* d_in, const int* in_sizes, int n_in,
                              void* d_out, int out_size, void* d_ws,
                              size_t ws_size, hipStream_t stream) {
  const float* x        = (const float*)d_in[0];
  const int*   edge_idx = (const int*)d_in[1];
  const int*   batch    = (const int*)d_in[2];
  const float* W_gat    = (const float*)d_in[3];
  const float* att_src  = (const float*)d_in[4];
  const float* att_dst  = (const float*)d_in[5];
  const float* b_gat    = (const float*)d_in[6];
  const float* W_gcn    = (const float*)d_in[7];
  const float* b_gcn    = (const float*)d_in[8];
  const float* W1       = (const float*)d_in[9];
  const float* b1       = (const float*)d_in[10];
  const float* W2       = (const float*)d_in[11];
  const float* b2       = (const float*)d_in[12];
  float* out = (float*)d_out;
  (void)in_sizes; (void)n_in; (void)out_size; (void)ws_size;

  char* ws = (char*)d_ws;
  size_t off = 0;
  auto alloc = [&](size_t bytes) -> void* {
    void* p = ws + off;
    off += (bytes + 255) & ~(size_t)255;
    return p;
  };
  // bufR: A_bf [MP_N][KP_GCN] (dead after GEMM_B), then out2 bf16 [NN][LD_H]
  char*  bufR     = (char*)alloc((size_t)MP_N * KP_GCN * 2);      // 48.1 MB
  __bf16* A_bf    = (__bf16*)bufR;
  __bf16* out2b   = (__bf16*)bufR;
  __bf16* z_bf    = (__bf16*)alloc((size_t)MP_N * LD_Z * 2);      // 57.8 MB
  __bf16* h2_bf   = (__bf16*)alloc((size_t)MP_N * LD_H * 2);      // 47.2 MB
  __bf16* x_bf    = (__bf16*)alloc((size_t)MP_N * KP_X * 2);      // 5.8 MB
  __bf16* WE      = (__bf16*)alloc((size_t)NH * 128 * 96 * 2);
  __bf16* WgcnT   = (__bf16*)alloc((size_t)NP_HID * KP_GCN * 2);
  __bf16* W1T     = (__bf16*)alloc((size_t)NP_W1 * KP_P * 2);
  __bf16* W2T     = (__bf16*)alloc((size_t)128 * LD_FC * 2);
  __bf16* pooled  = (__bf16*)alloc((size_t)MP_G * KP_P * 2);
  __bf16* hidfc   = (__bf16*)alloc((size_t)MP_G * LD_FC * 2);
  float* pb       = (float*)alloc((size_t)KP_GCN * 4);
  float* wsd      = (float*)alloc((size_t)FF * 2 * NH * 4);
  float* a_src_b  = (float*)alloc((size_t)NN * NH * 4);
  float* a_dst_b  = (float*)alloc((size_t)NN * NH * 4);
  float* p_csr    = (float*)alloc((size_t)ET * NH * 4);           // 10.8 MB
  int*   cnt      = (int*)alloc((size_t)NN * 4);
  int*   fill     = (int*)alloc((size_t)NN * 4);
  int*   row_ptr  = (int*)alloc((size_t)(NN + 1) * 4);
  int*   col_src  = (int*)alloc((size_t)ET * 4);
  int*   dst_csr  = (int*)alloc((size_t)ET * 4);
  int*   partial  = (int*)alloc((size_t)NBLK * 4);
  int*   lo       = (int*)alloc((size_t)GG * 4);
  int*   hi       = (int*)alloc((size_t)GG * 4);
  float* dinv     = (float*)alloc((size_t)NN * 4);

  prep_kernel<<<(C_TOT + 255) / 256, 256, 0, stream>>>(
      x, W_gat, att_src, att_dst, W_gcn, W1, W2, b_gat, x_bf, WE, WgcnT, W1T,
      W2T, pb, wsd, cnt, fill, lo, hi);

  adot_count_kernel<<<(NN * 2 * NH + 255) / 256, 256, 0, stream>>>(
      x, wsd, a_src_b, a_dst_b, edge_idx, batch, cnt, lo, hi);

  scan1_kernel<<<NBLK, 1024, 0, stream>>>(cnt, row_ptr, partial);
  scan3_kernel<<<(NN + 255) / 256, 256, 0, stream>>>(row_ptr, partial, cnt,
                                                     dinv);
  scatter_kernel<<<(ET + 255) / 256, 256, 0, stream>>>(edge_idx, row_ptr,
                                                       fill, col_src, dst_csr);
  pexp_kernel<<<(ET + 255) / 256, 256, 0, stream>>>(col_src, dst_csr,
                                                    a_src_b, a_dst_b, p_csr);

  gat_x_aggr_kernel<<<NN / 2, 256, 0, stream>>>(row_ptr, col_src, p_csr, x_bf,
                                                z_bf);
  gemm_head<<<dim3(NH, MP_N / MT), 256, 0, stream>>>(z_bf, WE, pb, A_bf);
  {  // GEMM_B: generic 128x128 DBUF + XCD swizzle (R11 measured 98us)
    mfma_gemm<true, 32, true><<<dim3(8 * 30 * 7), 256, 0, stream>>>(
        A_bf, WgcnT, nullptr, h2_bf, nullptr, NN, KP_GCN, HID, LD_H, 0,
        30, 7, MP_N / MT);
  }
  gcn_aggr_kernel<<<NN / 2, 256, 0, stream>>>(row_ptr, col_src, dinv, h2_bf,
                                              b_gcn, out2b);

  pool_kernel<<<GG, 128, 0, stream>>>(out2b, lo, hi, pooled);

  {  // GEMM_C: hidfc = relu(pooled @ W1 + b1)  (K=1600, KBC=64, DBUF)
    dim3 grid(NP_W1 / NT, MP_G / MT);
    mfma_gemm<true, 64, true><<<grid, 256, 0, stream>>>(
        pooled, W1T, nullptr, hidfc, b1, GG, KP_P, 1500, LD_FC, 1, 0, 0, 0);
  }
  {  // GEMM_D: out = hidfc @ W2 + b2  (fp32 out, K=1536, KBC=64, DBUF)
    dim3 grid(1, MP_G / MT);
    mfma_gemm<false, 64, true><<<grid, 256, 0, stream>>>(
        hidfc, W2T, out, nullptr, b2, GG, LD_FC, 128, 128, 0, 0, 0, 0);
  }
}